// Round 9
// baseline (99.206 us; speedup 1.0000x reference)
//
#include <hip/hip_runtime.h>
#include <hip/hip_bf16.h>

#define S_   8
#define N_   1024
#define KG_  16
#define MW_  64
#define CI_  128
#define CO_  256

typedef __attribute__((ext_vector_type(8))) short bf16x8;
typedef __attribute__((ext_vector_type(4))) float f32x4;

// ---------------------------------------------------------------------------
// Fused: W fp32->bf16 convert + circular sliding-window sums (bf16 out).
// win2[s][t][c] = win2[s][t+1024][c] = sum_{m<64} x[s][(t+m)%N][c]
// Output DUPLICATED across 2N rows so the GEMM needs no circular wrap.
// ---------------------------------------------------------------------------
__global__ __launch_bounds__(256) void win_kernel(const float* __restrict__ x,
                                                  const float* __restrict__ W,
                                                  __hip_bfloat16* __restrict__ win,
                                                  __hip_bfloat16* __restrict__ Wb) {
    __shared__ float lds[96][CI_];           // 48 KB
    const int b   = blockIdx.x;              // 0..255
    const int tid = threadIdx.x;

    // --- W conversion: 8 elems per thread ---
    {
        const int wi = (b * 256 + tid) * 8;
        const float4 v0 = *(const float4*)&W[wi];
        const float4 v1 = *(const float4*)&W[wi + 4];
        union { unsigned short u[8]; uint4 v; } o;
        __hip_bfloat16 h;
        h = __float2bfloat16(v0.x); o.u[0] = *(unsigned short*)&h;
        h = __float2bfloat16(v0.y); o.u[1] = *(unsigned short*)&h;
        h = __float2bfloat16(v0.z); o.u[2] = *(unsigned short*)&h;
        h = __float2bfloat16(v0.w); o.u[3] = *(unsigned short*)&h;
        h = __float2bfloat16(v1.x); o.u[4] = *(unsigned short*)&h;
        h = __float2bfloat16(v1.y); o.u[5] = *(unsigned short*)&h;
        h = __float2bfloat16(v1.z); o.u[6] = *(unsigned short*)&h;
        h = __float2bfloat16(v1.w); o.u[7] = *(unsigned short*)&h;
        *(uint4*)&Wb[wi] = o.v;
    }

    // --- sliding window ---
    const int s   = b >> 5;
    const int t0  = (b & 31) << 5;           // 32 t's per block
    const float* xs = x + (size_t)s * N_ * CI_;

    for (int e = tid * 4; e < 96 * CI_; e += 256 * 4) {
        const int r = e >> 7;
        const int c = e & (CI_ - 1);
        *(float4*)&lds[r][c] = *(const float4*)&xs[((t0 + r) & (N_ - 1)) * CI_ + c];
    }
    __syncthreads();

    const int c  = tid & (CI_ - 1);
    const int tb = (tid >> 7) << 4;          // 0 or 16
    float s0 = 0.f, s1 = 0.f, s2 = 0.f, s3 = 0.f;
    #pragma unroll
    for (int m = 0; m < MW_; m += 4) {
        s0 += lds[tb + m + 0][c];
        s1 += lds[tb + m + 1][c];
        s2 += lds[tb + m + 2][c];
        s3 += lds[tb + m + 3][c];
    }
    float w = (s0 + s1) + (s2 + s3);
    __hip_bfloat16* wo = win + (size_t)s * (2 * N_) * CI_;
    {
        const int row = t0 + tb;
        const __hip_bfloat16 hv = __float2bfloat16(w);
        wo[row * CI_ + c] = hv;
        wo[(row + N_) * CI_ + c] = hv;
    }
    #pragma unroll
    for (int t = 1; t < 16; ++t) {
        w += lds[tb + t - 1 + MW_][c] - lds[tb + t - 1][c];
        const int row = t0 + tb + t;
        const __hip_bfloat16 hv = __float2bfloat16(w);
        wo[row * CI_ + c] = hv;
        wo[(row + N_) * CI_ + c] = hv;
    }
}

// ---------------------------------------------------------------------------
// out[s,n,o] = sum_{g,c} win[s,(n+64g)%N,c] * W[g,o,c]
// Register MFMA GEMM, K-split x4, ALL FRAGMENTS IN NAMED REGISTERS (macros,
// no arrays / lambdas -> no scratch; round-7's VGPR_Count=76 proved the
// array version spilled every fragment to scratch).
// Block = 256 threads (4 waves), tile 64x64; wave wv covers groups
// wv*4..wv*4+3 (16 K32-steps); 2-deep ping-pong prefetch (p/q sets).
// win is row-duplicated (2N rows) so all addresses are base + static offset.
// Partials reduced via 4 LDS buffers + 1 barrier. Grid 512 = 2 blocks/CU
// = 8 waves/CU. XCD-pinned: s = blockIdx.x & 7.
// ---------------------------------------------------------------------------
__global__ __launch_bounds__(256, 2) void gemm_kernel(const __hip_bfloat16* __restrict__ winb,
                                                      const __hip_bfloat16* __restrict__ Wb,
                                                      float* __restrict__ out) {
    __shared__ __align__(16) float red[4][64][68];   // 69.6 KB

    const int tid = threadIdx.x;
    const int l   = tid & 63;
    const int wv  = tid >> 6;                // 0..3
    const int s   = blockIdx.x & 7;          // XCD-pinned sample index
    const int rem = blockIdx.x >> 3;         // 0..63
    const int n0  = (rem & 15) << 6;         // 64-row tile
    const int o0  = (rem >> 4) << 6;         // 64-col tile

    const int fr  = l & 15;
    const int kq  = l >> 4;                  // 0..3

    // Per-lane base pointers; every load below is base + constant offset.
    const unsigned short* Ab = (const unsigned short*)winb
        + ((size_t)s * 2 * N_ + (size_t)(n0 + (wv << 2) * MW_ + fr)) * CI_ + kq * 8;
    const unsigned short* Bb = (const unsigned short*)Wb
        + ((size_t)((wv << 2) * CO_ + o0 + fr)) * CI_ + kq * 8;

#define AOFF(T,i) (((((T) >> 2) * MW_) + ((i) * 16)) * CI_ + (((T) & 3) * 32))
#define BOFF(T,j) (((((T) >> 2) * CO_) + ((j) * 16)) * CI_ + (((T) & 3) * 32))

    f32x4 c00 = {0.f,0.f,0.f,0.f}, c01 = {0.f,0.f,0.f,0.f}, c02 = {0.f,0.f,0.f,0.f}, c03 = {0.f,0.f,0.f,0.f};
    f32x4 c10 = {0.f,0.f,0.f,0.f}, c11 = {0.f,0.f,0.f,0.f}, c12 = {0.f,0.f,0.f,0.f}, c13 = {0.f,0.f,0.f,0.f};
    f32x4 c20 = {0.f,0.f,0.f,0.f}, c21 = {0.f,0.f,0.f,0.f}, c22 = {0.f,0.f,0.f,0.f}, c23 = {0.f,0.f,0.f,0.f};
    f32x4 c30 = {0.f,0.f,0.f,0.f}, c31 = {0.f,0.f,0.f,0.f}, c32 = {0.f,0.f,0.f,0.f}, c33 = {0.f,0.f,0.f,0.f};

    bf16x8 pa0, pa1, pa2, pa3, pb0, pb1, pb2, pb3;
    bf16x8 qa0, qa1, qa2, qa3, qb0, qb1, qb2, qb3;

#define LOADSET(T, S) \
    S##a0 = *(const bf16x8*)(Ab + AOFF(T,0)); \
    S##a1 = *(const bf16x8*)(Ab + AOFF(T,1)); \
    S##a2 = *(const bf16x8*)(Ab + AOFF(T,2)); \
    S##a3 = *(const bf16x8*)(Ab + AOFF(T,3)); \
    S##b0 = *(const bf16x8*)(Bb + BOFF(T,0)); \
    S##b1 = *(const bf16x8*)(Bb + BOFF(T,1)); \
    S##b2 = *(const bf16x8*)(Bb + BOFF(T,2)); \
    S##b3 = *(const bf16x8*)(Bb + BOFF(T,3));

#define MM(A, B, C) C = __builtin_amdgcn_mfma_f32_16x16x32_bf16(A, B, C, 0, 0, 0)

#define COMPUTESET(S) \
    MM(S##a0, S##b0, c00); MM(S##a0, S##b1, c01); MM(S##a0, S##b2, c02); MM(S##a0, S##b3, c03); \
    MM(S##a1, S##b0, c10); MM(S##a1, S##b1, c11); MM(S##a1, S##b2, c12); MM(S##a1, S##b3, c13); \
    MM(S##a2, S##b0, c20); MM(S##a2, S##b1, c21); MM(S##a2, S##b2, c22); MM(S##a2, S##b3, c23); \
    MM(S##a3, S##b0, c30); MM(S##a3, S##b1, c31); MM(S##a3, S##b2, c32); MM(S##a3, S##b3, c33);

    LOADSET(0, p)
    LOADSET(1, q)

    COMPUTESET(p) LOADSET(2,  p)
    COMPUTESET(q) LOADSET(3,  q)
    COMPUTESET(p) LOADSET(4,  p)
    COMPUTESET(q) LOADSET(5,  q)
    COMPUTESET(p) LOADSET(6,  p)
    COMPUTESET(q) LOADSET(7,  q)
    COMPUTESET(p) LOADSET(8,  p)
    COMPUTESET(q) LOADSET(9,  q)
    COMPUTESET(p) LOADSET(10, p)
    COMPUTESET(q) LOADSET(11, q)
    COMPUTESET(p) LOADSET(12, p)
    COMPUTESET(q) LOADSET(13, q)
    COMPUTESET(p) LOADSET(14, p)
    COMPUTESET(q) LOADSET(15, q)
    COMPUTESET(p)
    COMPUTESET(q)

    // Store partials: D layout col = lane&15, row = (lane>>4)*4 + reg (r2-r8)
#define STACC(C, i, j) \
    red[wv][(i)*16 + kq*4 + 0][(j)*16 + fr] = C[0]; \
    red[wv][(i)*16 + kq*4 + 1][(j)*16 + fr] = C[1]; \
    red[wv][(i)*16 + kq*4 + 2][(j)*16 + fr] = C[2]; \
    red[wv][(i)*16 + kq*4 + 3][(j)*16 + fr] = C[3];

    STACC(c00,0,0) STACC(c01,0,1) STACC(c02,0,2) STACC(c03,0,3)
    STACC(c10,1,0) STACC(c11,1,1) STACC(c12,1,2) STACC(c13,1,3)
    STACC(c20,2,0) STACC(c21,2,1) STACC(c22,2,2) STACC(c23,2,3)
    STACC(c30,3,0) STACC(c31,3,1) STACC(c32,3,2) STACC(c33,3,3)

    __syncthreads();

    // Cooperative 4-way sum + coalesced write: thread t -> row t>>2, 16 cols.
    const int r  = tid >> 2;
    const int cb = (tid & 3) << 4;
    float* op = out + ((size_t)(s * N_ + n0 + r) * CO_) + o0 + cb;
    #pragma unroll
    for (int q2 = 0; q2 < 4; ++q2) {
        const f32x4 v0 = *(const f32x4*)&red[0][r][cb + q2 * 4];
        const f32x4 v1 = *(const f32x4*)&red[1][r][cb + q2 * 4];
        const f32x4 v2 = *(const f32x4*)&red[2][r][cb + q2 * 4];
        const f32x4 v3 = *(const f32x4*)&red[3][r][cb + q2 * 4];
        const f32x4 v  = (v0 + v1) + (v2 + v3);
        *(f32x4*)&op[q2 * 4] = v;
    }
}

extern "C" void kernel_launch(void* const* d_in, const int* in_sizes, int n_in,
                              void* d_out, int out_size, void* d_ws, size_t ws_size,
                              hipStream_t stream) {
    const float* x = (const float*)d_in[0];   // [S, N, CI]
    const float* W = (const float*)d_in[1];   // [K, CO, CI]

    __hip_bfloat16* winb = (__hip_bfloat16*)d_ws;                               // 4 MB (2N rows)
    __hip_bfloat16* Wbb  = (__hip_bfloat16*)((char*)d_ws +
                              (size_t)S_ * 2 * N_ * CI_ * sizeof(__hip_bfloat16)); // 1 MB
    float* out = (float*)d_out;               // [S, N, CO] fp32

    win_kernel<<<256, 256, 0, stream>>>(x, W, winb, Wbb);
    gemm_kernel<<<512, 256, 0, stream>>>(winb, Wbb, out);
}